// Round 1
// baseline (132.297 us; speedup 1.0000x reference)
//
#include <hip/hip_runtime.h>

#define IMG_H 1080
#define IMG_W 1920
#define NBATCH 8
#define TW 256
#define TH 24
#define SROWS (TH + 4)   // 28 staged rows (2-px halo each side)
#define SCOLS (TW + 4)   // 260 staged cols
#define STRIP 6          // output rows per thread (TH / 4 waves)

// Fused Shi-Tomasi: stage image tile in LDS, per-lane 4-col strip with
// separable Sobel + rolling 3-row box-sum in registers. Double-clamp
// (pad-replicate applied twice in the reference) handled exactly:
//  - rows: staged-row indices computed with clamp(clamp(.)+d) per product row
//  - cols: only virtual cols -1 and W differ; fixed per-lane at image edges.
__global__ __launch_bounds__(256, 4)
void shi_tomasi_kernel(const float* __restrict__ img, float* __restrict__ out) {
    __shared__ float S[SROWS * SCOLS];
    const int x0 = blockIdx.x * TW;
    const int y0 = blockIdx.y * TH;
    const int b  = blockIdx.z;
    const float* g = img + (size_t)b * (IMG_H * IMG_W);

    if (x0 >= 2 && x0 + SCOLS - 2 <= IMG_W) {
        // fast staging: interior cols j=2..257 via float4 global loads
        for (int q = threadIdx.x; q < SROWS * 64; q += 256) {
            const int row = q >> 6, lane = q & 63;
            int gr = y0 + row - 2; gr = max(0, min(IMG_H - 1, gr));
            const float* src = g + (size_t)gr * IMG_W + (x0 + 4 * lane);
            const float4 v = *(const float4*)src;
            float* d = S + row * SCOLS + 2 + 4 * lane;
            ((float2*)d)[0] = make_float2(v.x, v.y);
            ((float2*)d)[1] = make_float2(v.z, v.w);
        }
        if (threadIdx.x < SROWS * 4) {   // halo cols j = 0,1,258,259
            const int row = threadIdx.x >> 2, e = threadIdx.x & 3;
            const int j = (e < 2) ? e : (TW + e);
            int gr = y0 + row - 2; gr = max(0, min(IMG_H - 1, gr));
            const int gc = x0 + j - 2;   // in range for interior tiles
            S[row * SCOLS + j] = g[(size_t)gr * IMG_W + gc];
        }
    } else {
        // generic staging with full clamping (leftmost/rightmost x-tiles)
        for (int p = threadIdx.x; p < SROWS * SCOLS; p += 256) {
            const int row = p / SCOLS;
            const int col = p - row * SCOLS;
            int gr = y0 + row - 2; gr = max(0, min(IMG_H - 1, gr));
            int gc = x0 + col - 2; gc = max(0, min(IMG_W - 1, gc));
            S[row * SCOLS + col] = g[(size_t)gr * IMG_W + gc];
        }
    }
    __syncthreads();

    const int tx = threadIdx.x & 63;
    const int ty = threadIdx.x >> 6;
    const int vb = x0 + 4 * tx;          // global col of this lane's output 0
    if (vb >= IMG_W) return;             // dead lanes in the partial x-tile
    const int s0 = ty * STRIP;           // first output row of this strip
    const bool fixL = (vb == 0);
    const bool fixR = (vb == IMG_W - 4);

    float* orow = out + ((size_t)b * IMG_H + (y0 + s0)) * IMG_W + vb;

    float h[3][12];   // rolling ring of horizontal 3-sums: [row%3][xx0-3,yy0-3,xy0-3]

    #pragma unroll
    for (int rr = 0; rr < STRIP + 2; ++rr) {
        const int r = s0 - 1 + rr;                     // virtual product row
        int pr = y0 + r; pr = max(0, min(IMG_H - 1, pr));
        const int im = max(0, pr - 1) - y0 + 2;        // staged rows (double-clamp exact)
        const int i0 = pr - y0 + 2;
        const int ip = min(IMG_H - 1, pr + 1) - y0 + 2;

        const float4* Rm = (const float4*)(S + im * SCOLS);
        const float4* R0 = (const float4*)(S + i0 * SCOLS);
        const float4* Rp = (const float4*)(S + ip * SCOLS);
        const float4 mA = Rm[tx], mB = Rm[tx + 1];
        const float4 zA = R0[tx], zB = R0[tx + 1];
        const float4 pA = Rp[tx], pB = Rp[tx + 1];
        const float m[8] = {mA.x, mA.y, mA.z, mA.w, mB.x, mB.y, mB.z, mB.w};
        const float z[8] = {zA.x, zA.y, zA.z, zA.w, zB.x, zB.y, zB.z, zB.w};
        const float p[8] = {pA.x, pA.y, pA.z, pA.w, pB.x, pB.y, pB.z, pB.w};

        // separable Sobel column partials over window cols vb-2..vb+5
        float A[8], Bv[8];
        #pragma unroll
        for (int s = 0; s < 8; ++s) {
            A[s]  = m[s] + 2.0f * z[s] + p[s];
            Bv[s] = p[s] - m[s];
        }
        // gradients at product cols (virtual vb-1..vb+4)
        float Ix[6], Iy[6];
        #pragma unroll
        for (int s = 0; s < 6; ++s) {
            Ix[s] = A[s + 2] - A[s];
            Iy[s] = Bv[s] + 2.0f * Bv[s + 1] + Bv[s + 2];
        }
        // double-clamp column fixes at the image edges:
        // virtual col -1 == P_true[0], sobel cols (0,0,1) = slots (2,2,3)
        if (fixL) { Ix[0] = A[3] - A[2]; Iy[0] = 3.0f * Bv[2] + Bv[3]; }
        // virtual col W == P_true[W-1], sobel cols (W-2,W-1,W-1) = slots (4,5,5)
        if (fixR) { Ix[5] = A[5] - A[4]; Iy[5] = Bv[4] + 3.0f * Bv[5]; }

        float pxx[6], pyy[6], pxy[6];
        #pragma unroll
        for (int s = 0; s < 6; ++s) {
            pxx[s] = Ix[s] * Ix[s];
            pyy[s] = Iy[s] * Iy[s];
            pxy[s] = Ix[s] * Iy[s];
        }
        float* hr = h[rr % 3];
        #pragma unroll
        for (int o = 0; o < 4; ++o) {
            hr[o]     = pxx[o] + pxx[o + 1] + pxx[o + 2];
            hr[4 + o] = pyy[o] + pyy[o + 1] + pyy[o + 2];
            hr[8 + o] = pxy[o] + pxy[o + 1] + pxy[o + 2];
        }
        if (rr >= 2) {
            const float* h0 = h[(rr - 2) % 3];
            const float* h1 = h[(rr - 1) % 3];
            float rv[4];
            #pragma unroll
            for (int o = 0; o < 4; ++o) {
                const float sxx = h0[o]     + h1[o]     + hr[o];
                const float syy = h0[4 + o] + h1[4 + o] + hr[4 + o];
                const float sxy = h0[8 + o] + h1[8 + o] + hr[8 + o];
                const float ht   = 0.5f * (sxx + syy);
                const float dh   = 0.5f * (sxx - syy);
                const float disc = dh * dh + sxy * sxy + 1e-10f;
                const float lam  = ht - sqrtf(disc);
                rv[o] = fmaxf(lam, 0.0f);
            }
            *(float4*)orow = make_float4(rv[0], rv[1], rv[2], rv[3]);
            orow += IMG_W;
        }
    }
}

extern "C" void kernel_launch(void* const* d_in, const int* in_sizes, int n_in,
                              void* d_out, int out_size, void* d_ws, size_t ws_size,
                              hipStream_t stream) {
    const float* img = (const float*)d_in[0];
    float* out = (float*)d_out;
    dim3 grid((IMG_W + TW - 1) / TW, IMG_H / TH, NBATCH);
    shi_tomasi_kernel<<<grid, 256, 0, stream>>>(img, out);
}

// Round 2
// 125.444 us; speedup vs baseline: 1.0546x; 1.0546x over previous
//
#include <hip/hip_runtime.h>

#define IMG_H 1080
#define IMG_W 1920
#define NBATCH 8

// LDS-free fused Shi-Tomasi.
// Lane = 4 output cols x 9 output rows. Block = 32 col-groups x 8 strips
// (128 cols x 72 rows). Grid 15 x 15 x 8 -- exact cover, no dead lanes.
//
// Per input row compute separable partials ONCE and reuse across the 3
// product rows that touch it (3-deep register ring):
//   hd[t] = z[t+2]-z[t]          (-> Ix = hd_m + 2 hd_z + hd_p)
//   hs[t] = z[t] + 2 z[t+1] + z[t+2]  (-> Iy = hs_p - hs_m)
// Products -> horizontal 3-sums -> 3-deep h-ring -> vertical 3-sum + eig.
//
// Reference pads replicate TWICE (before Sobel, before box-sum):
//  rows: schedule-keyed ring loads row clamp(sr); exact for all interior vr.
//        vr=-1 (top) equals P(0): copy h computed at vr=0 into its slot.
//        vr=H (bottom) equals P(H-1): copy previous h slot.
//  cols: single-clamp replicate baked into edge-lane z[] shuffle; the
//        double-clamped virtual cols -1 / W recomputed via hfd/hfs partials.
__global__ __launch_bounds__(256, 4)
void shi_tomasi_kernel(const float* __restrict__ img, float* __restrict__ out) {
    const int cg    = threadIdx.x & 31;           // col-group within block
    const int strip = threadIdx.x >> 5;           // 0..7
    const int vb = blockIdx.x * 128 + cg * 4;     // first output col
    const int s0 = blockIdx.y * 72 + strip * 9;   // first output row
    const int b  = blockIdx.z;
    const float* g = img + (size_t)b * (IMG_H * IMG_W);

    const bool eL = (vb == 0);
    const bool eR = (vb == IMG_W - 4);
    const int  o0 = eL ? 0 : (eR ? vb - 4 : vb - 2);   // even -> 8B-aligned
    const bool topFix = (s0 == 0);
    const bool botFix = (s0 + 9 == IMG_H);

    float hdR[3][6], hsR[3][6], hfd[3], hfs[3], h[3][12];

    auto load_row = [&](int lr, float* hd, float* hs, float& fd, float& fs) {
        const float* rp = g + (size_t)lr * IMG_W + o0;
        const float2 p0 = *(const float2*)(rp);
        const float2 p1 = *(const float2*)(rp + 2);
        const float2 p2 = *(const float2*)(rp + 4);
        const float2 p3 = *(const float2*)(rp + 6);
        float z0=p0.x, z1=p0.y, z2=p1.x, z3=p1.y, z4=p2.x, z5=p2.y, z6=p3.x, z7=p3.y;
        // edge shuffles: map loaded cols to virtual cols vb-2..vb+5 with
        // single-pixel replicate (z order chosen so sources aren't clobbered)
        if (eL) { z7=z5; z6=z4; z5=z3; z4=z2; z3=z1; z2=z0; z1=z0; }
        if (eR) { z0=z2; z1=z3; z2=z4; z3=z5; z4=z6; z5=z7; z6=z7; }
        hd[0]=z2-z0; hd[1]=z3-z1; hd[2]=z4-z2; hd[3]=z5-z3; hd[4]=z6-z4; hd[5]=z7-z5;
        hs[0]=z0+2.0f*z1+z2; hs[1]=z1+2.0f*z2+z3; hs[2]=z2+2.0f*z3+z4;
        hs[3]=z3+2.0f*z4+z5; hs[4]=z4+2.0f*z5+z6; hs[5]=z5+2.0f*z6+z7;
        // double-clamped edge column partials (virtual col -1 / col W)
        fd = eR ? (z5-z4) : (z3-z2);
        fs = eR ? (z4+3.0f*z5) : (3.0f*z2+z3);
    };

    // preload ring slots 0,1 (schedule rows s0-2, s0-1)
    load_row(max(s0-2,0), hdR[0], hsR[0], hfd[0], hfs[0]);
    load_row(max(s0-1,0), hdR[1], hsR[1], hfd[1], hfs[1]);

    float* orow = out + ((size_t)b * IMG_H + s0) * IMG_W + vb;

    #pragma unroll
    for (int rr = 0; rr < 11; ++rr) {           // product row vr = s0-1+rr
        const int sm = rr % 3;                  // slot: vr-1
        const int sz = (rr + 1) % 3;            // slot: vr
        const int sp = (rr + 2) % 3;            // slot: vr+1 (load now)
        load_row(min(s0 + rr, IMG_H - 1), hdR[sp], hsR[sp], hfd[sp], hfs[sp]);

        float Ix[6], Iy[6];
        #pragma unroll
        for (int t = 0; t < 6; ++t) {
            Ix[t] = hdR[sm][t] + 2.0f * hdR[sz][t] + hdR[sp][t];
            Iy[t] = hsR[sp][t] - hsR[sm][t];
        }
        const float ixf = hfd[sm] + 2.0f * hfd[sz] + hfd[sp];
        const float iyf = hfs[sp] - hfs[sm];
        if (eL) { Ix[0] = ixf; Iy[0] = iyf; }
        if (eR) { Ix[5] = ixf; Iy[5] = iyf; }

        float pxx[6], pyy[6], pxy[6];
        #pragma unroll
        for (int t = 0; t < 6; ++t) {
            pxx[t] = Ix[t] * Ix[t];
            pyy[t] = Iy[t] * Iy[t];
            pxy[t] = Ix[t] * Iy[t];
        }
        float* hr = h[rr % 3];
        #pragma unroll
        for (int o = 0; o < 4; ++o) {
            hr[o]     = pxx[o] + pxx[o+1] + pxx[o+2];
            hr[4 + o] = pyy[o] + pyy[o+1] + pyy[o+2];
            hr[8 + o] = pxy[o] + pxy[o+1] + pxy[o+2];
        }
        // top: P(vr=-1) == P(vr=0); fix slot 0 once vr=0 is computed
        if (rr == 1) {
            #pragma unroll
            for (int q = 0; q < 12; ++q) if (topFix) h[0][q] = hr[q];
        }
        // bottom: P(vr=H) == P(vr=H-1); overwrite current with previous
        if (rr == 10) {
            const float* hprev = h[(rr - 1) % 3];
            #pragma unroll
            for (int q = 0; q < 12; ++q) if (botFix) hr[q] = hprev[q];
        }

        if (rr >= 2) {
            const float* h0 = h[(rr - 2) % 3];
            const float* h1 = h[(rr - 1) % 3];
            const float* h2 = h[rr % 3];
            float rv[4];
            #pragma unroll
            for (int o = 0; o < 4; ++o) {
                const float sxx = h0[o]     + h1[o]     + h2[o];
                const float syy = h0[4 + o] + h1[4 + o] + h2[4 + o];
                const float sxy = h0[8 + o] + h1[8 + o] + h2[8 + o];
                const float ht   = 0.5f * (sxx + syy);
                const float dh   = 0.5f * (sxx - syy);
                const float disc = fmaf(dh, dh, fmaf(sxy, sxy, 1e-10f));
                rv[o] = fmaxf(ht - sqrtf(disc), 0.0f);
            }
            *(float4*)orow = make_float4(rv[0], rv[1], rv[2], rv[3]);
            orow += IMG_W;
        }
    }
}

extern "C" void kernel_launch(void* const* d_in, const int* in_sizes, int n_in,
                              void* d_out, int out_size, void* d_ws, size_t ws_size,
                              hipStream_t stream) {
    const float* img = (const float*)d_in[0];
    float* out = (float*)d_out;
    dim3 grid(IMG_W / 128, IMG_H / 72, NBATCH);   // 15 x 15 x 8
    shi_tomasi_kernel<<<grid, 256, 0, stream>>>(img, out);
}

// Round 3
// 121.933 us; speedup vs baseline: 1.0850x; 1.0288x over previous
//
#include <hip/hip_runtime.h>

#define IMG_H 1080
#define IMG_W 1920
#define NBATCH 8

// 8-byte-aligned 4-float vector: lets us issue 16B global loads at the
// o0 = vb-2 (8B-aligned) window base without UB / forced splitting.
struct __attribute__((aligned(8))) f4u { float a, b, c, d; };

// LDS-free fused Shi-Tomasi, MLP-restructured.
// Same geometry + edge algebra as R2 (validated): lane = 4 cols x 9 rows,
// block = 128 cols x 72 rows, grid 15 x 15 x 8 exact.
// New: 5-deep raw-pixel register ring, prefetch distance 4 -> ~8 vmem loads
// in flight per wave (R2 had ~1-2, exposing full L3/HBM latency per row).
__global__ __launch_bounds__(256, 3)
void shi_tomasi_kernel(const float* __restrict__ img, float* __restrict__ out) {
    const int cg    = threadIdx.x & 31;           // col-group within block
    const int strip = threadIdx.x >> 5;           // 0..7
    const int vb = blockIdx.x * 128 + cg * 4;     // first output col
    const int s0 = blockIdx.y * 72 + strip * 9;   // first output row
    const int b  = blockIdx.z;
    const float* g = img + (size_t)b * (IMG_H * IMG_W);

    const bool eL = (vb == 0);
    const bool eR = (vb == IMG_W - 4);
    const int  o0 = eL ? 0 : (eR ? vb - 4 : vb - 2);   // 8B-aligned window base
    const bool topFix = (s0 == 0);
    const bool botFix = (s0 + 9 == IMG_H);

    float raw[5][8];                    // raw pixel ring (schedule row k -> k%5)
    float hdR[3][6], hsR[3][6], hfd[3], hfs[3], h[3][12];

    // issue loads for schedule row s0-2+k into raw[k%5]; the actual waitcnt
    // lands at first USE (partials), so these stay in flight.
    auto issue = [&](int k) {
        int lr = s0 - 2 + k; lr = max(0, min(IMG_H - 1, lr));
        const float* rp = g + (size_t)lr * IMG_W + o0;
        const f4u va = *(const f4u*)rp;
        const f4u vc = *(const f4u*)(rp + 4);
        float* r = raw[k % 5];
        r[0] = va.a; r[1] = va.b; r[2] = va.c; r[3] = va.d;
        r[4] = vc.a; r[5] = vc.b; r[6] = vc.c; r[7] = vc.d;
    };

    #pragma unroll
    for (int k = 0; k < 4; ++k) issue(k);   // preload rows s0-2 .. s0+1

    float* orow = out + ((size_t)b * IMG_H + s0) * IMG_W + vb;

    #pragma unroll
    for (int k = 0; k < 13; ++k) {          // schedule row sr = s0-2+k
        if (k + 4 < 13) issue(k + 4);       // prefetch distance 4

        // ---- partials for schedule row k (consumes raw[k%5]) ----
        {
            const float* r = raw[k % 5];
            float z0=r[0], z1=r[1], z2=r[2], z3=r[3], z4=r[4], z5=r[5], z6=r[6], z7=r[7];
            // map loaded cols -> virtual cols vb-2..vb+5 with single replicate
            if (eL) { z7=z5; z6=z4; z5=z3; z4=z2; z3=z1; z2=z0; z1=z0; }
            if (eR) { z0=z2; z1=z3; z2=z4; z3=z5; z4=z6; z5=z7; z6=z7; }
            float* hd = hdR[k % 3];
            float* hs = hsR[k % 3];
            hd[0]=z2-z0; hd[1]=z3-z1; hd[2]=z4-z2; hd[3]=z5-z3; hd[4]=z6-z4; hd[5]=z7-z5;
            hs[0]=z0+2.0f*z1+z2; hs[1]=z1+2.0f*z2+z3; hs[2]=z2+2.0f*z3+z4;
            hs[3]=z3+2.0f*z4+z5; hs[4]=z4+2.0f*z5+z6; hs[5]=z5+2.0f*z6+z7;
            // double-clamped edge column partials (virtual col -1 / col W)
            hfd[k % 3] = eR ? (z5-z4) : (z3-z2);
            hfs[k % 3] = eR ? (z4+3.0f*z5) : (3.0f*z2+z3);
        }

        // ---- product row vr = s0-3+k (valid for k>=2) ----
        if (k >= 2) {
            const int rr = k - 2;
            const int sm = rr % 3;          // row vr-1
            const int sz = (rr + 1) % 3;    // row vr
            const int sp = (rr + 2) % 3;    // row vr+1 (just computed)

            float Ix[6], Iy[6];
            #pragma unroll
            for (int t = 0; t < 6; ++t) {
                Ix[t] = hdR[sm][t] + 2.0f * hdR[sz][t] + hdR[sp][t];
                Iy[t] = hsR[sp][t] - hsR[sm][t];
            }
            const float ixf = hfd[sm] + 2.0f * hfd[sz] + hfd[sp];
            const float iyf = hfs[sp] - hfs[sm];
            if (eL) { Ix[0] = ixf; Iy[0] = iyf; }
            if (eR) { Ix[5] = ixf; Iy[5] = iyf; }

            float pxx[6], pyy[6], pxy[6];
            #pragma unroll
            for (int t = 0; t < 6; ++t) {
                pxx[t] = Ix[t] * Ix[t];
                pyy[t] = Iy[t] * Iy[t];
                pxy[t] = Ix[t] * Iy[t];
            }
            float* hr = h[rr % 3];
            #pragma unroll
            for (int o = 0; o < 4; ++o) {
                hr[o]     = pxx[o] + pxx[o+1] + pxx[o+2];
                hr[4 + o] = pyy[o] + pyy[o+1] + pyy[o+2];
                hr[8 + o] = pxy[o] + pxy[o+1] + pxy[o+2];
            }
            // top: P(vr=-1) == P(vr=0)
            if (rr == 1) {
                #pragma unroll
                for (int q = 0; q < 12; ++q) if (topFix) h[0][q] = hr[q];
            }
            // bottom: P(vr=H) == P(vr=H-1)
            if (rr == 10) {
                const float* hprev = h[(rr - 1) % 3];
                #pragma unroll
                for (int q = 0; q < 12; ++q) if (botFix) hr[q] = hprev[q];
            }

            if (rr >= 2) {
                const float* h0 = h[(rr - 2) % 3];
                const float* h1 = h[(rr - 1) % 3];
                const float* h2 = hr;
                float rv[4];
                #pragma unroll
                for (int o = 0; o < 4; ++o) {
                    const float sxx = h0[o]     + h1[o]     + h2[o];
                    const float syy = h0[4 + o] + h1[4 + o] + h2[4 + o];
                    const float sxy = h0[8 + o] + h1[8 + o] + h2[8 + o];
                    const float ht   = 0.5f * (sxx + syy);
                    const float dh   = 0.5f * (sxx - syy);
                    const float disc = fmaf(dh, dh, fmaf(sxy, sxy, 1e-10f));
                    rv[o] = fmaxf(ht - sqrtf(disc), 0.0f);
                }
                *(float4*)orow = make_float4(rv[0], rv[1], rv[2], rv[3]);
                orow += IMG_W;
            }
        }
    }
}

extern "C" void kernel_launch(void* const* d_in, const int* in_sizes, int n_in,
                              void* d_out, int out_size, void* d_ws, size_t ws_size,
                              hipStream_t stream) {
    const float* img = (const float*)d_in[0];
    float* out = (float*)d_out;
    dim3 grid(IMG_W / 128, IMG_H / 72, NBATCH);   // 15 x 15 x 8
    shi_tomasi_kernel<<<grid, 256, 0, stream>>>(img, out);
}